// Round 1
// 406.906 us; speedup vs baseline: 1.0284x; 1.0284x over previous
//
#include <hip/hip_runtime.h>
#include <hip/hip_bf16.h>
#include <math.h>

// Problem constants
#define HD 1024     // hidden H
#define ID 512      // moe intermediate I
#define NE 32       // n experts
#define NT 2048     // tokens T = B*S
#define NG 4        // n_group
#define SHI 1024    // shared intermediate I*N_SHARED
#define SCALE 2.5f

// MFMA GEMM tile params (old fallback path)
#define BN 64
#define BK 32
#define LDA 40      // LDS row stride in bf16 (32 + 8 pad -> 80B rows)

typedef __bf16 bf16_t;
typedef __attribute__((ext_vector_type(8))) __bf16 bf16x8;
typedef __attribute__((ext_vector_type(4))) __bf16 bf16x4;
typedef __attribute__((ext_vector_type(4))) float f32x4;

// async global->LDS, 16B per lane; LDS dest must be wave-uniform base (+lane*16 implied)
__device__ __forceinline__ void gld16(const bf16_t* g, bf16_t* l) {
    __builtin_amdgcn_global_load_lds(
        (__attribute__((address_space(1))) void*)g,
        (__attribute__((address_space(3))) void*)l,
        16, 0, 0);
}

// ---------------- fp32 -> bf16 conversion pass (weights + hs), one fused kernel ----------------
#define CH_G 2097152LL    // gate/up/down chunks (16.78M elems / 8)
#define CH_S 131072LL     // shared tensors chunks (1.05M / 8)
#define CH_H 262144LL     // hs chunks (2.10M / 8)
#define CH_TOT (3*CH_G + 3*CH_S + CH_H)

__global__ void __launch_bounds__(256) convert_all(
    const float* __restrict__ g, const float* __restrict__ u, const float* __restrict__ d,
    const float* __restrict__ sg, const float* __restrict__ su, const float* __restrict__ sd,
    const float* __restrict__ hs, bf16_t* __restrict__ dst)
{
    for (long long c = blockIdx.x * 256LL + threadIdx.x; c < CH_TOT; c += (long long)gridDim.x * 256LL) {
        const float* src;
        long long r = c;
        if (r < CH_G)                   src = g  + (size_t)r * 8;
        else if ((r -= CH_G) < CH_G)    src = u  + (size_t)r * 8;
        else if ((r -= CH_G) < CH_G)    src = d  + (size_t)r * 8;
        else if ((r -= CH_G) < CH_S)    src = sg + (size_t)r * 8;
        else if ((r -= CH_S) < CH_S)    src = su + (size_t)r * 8;
        else if ((r -= CH_S) < CH_S)    src = sd + (size_t)r * 8;
        else { r -= CH_S;               src = hs + (size_t)r * 8; }
        float4 a = *(const float4*)src;
        float4 b = *(const float4*)(src + 4);
        bf16x8 o;
        o[0] = (__bf16)a.x; o[1] = (__bf16)a.y; o[2] = (__bf16)a.z; o[3] = (__bf16)a.w;
        o[4] = (__bf16)b.x; o[5] = (__bf16)b.y; o[6] = (__bf16)b.z; o[7] = (__bf16)b.w;
        *(bf16x8*)(dst + (size_t)c * 8) = o;
    }
}

// ---------------- router stage 1: logits GEMM + zero counts ----------------
#define LTOK 8
#define LKC 64
__global__ void __launch_bounds__(256) logits_kernel(
    const float* __restrict__ hs, const float* __restrict__ rw,
    float* __restrict__ logits, int* __restrict__ counts)
{
    if (blockIdx.x == 0 && threadIdx.x < NE) counts[threadIdx.x] = 0;

    __shared__ float Xs[LTOK][68];
    __shared__ float Ws[NE][65];

    int tid = threadIdx.x;
    int t0 = blockIdx.x * LTOK;
    int tslot = tid >> 5, ecol = tid & 31;
    float acc = 0.f;

    for (int k0 = 0; k0 < HD; k0 += LKC) {
        if (tid < 128) {
            int row = tid >> 4, q = tid & 15;
            float4 v = *(const float4*)(hs + (size_t)(t0 + row) * HD + k0 + q * 4);
            *(float4*)(&Xs[row][q * 4]) = v;
        }
        #pragma unroll
        for (int i = 0; i < 8; ++i) {
            int idx = i * 256 + tid;
            int e = idx >> 6, kk = idx & 63;
            Ws[e][kk] = rw[(size_t)e * HD + k0 + kk];
        }
        __syncthreads();
        #pragma unroll 8
        for (int kk = 0; kk < LKC; ++kk)
            acc += Xs[tslot][kk] * Ws[ecol][kk];
        __syncthreads();
    }
    logits[(size_t)(t0 + tslot) * NE + ecol] = acc;
}

// ---------------- router stage 2: per-token top-k ----------------
__global__ void __launch_bounds__(256) topk_kernel(
    const float* __restrict__ logits, const float* __restrict__ rb,
    float* __restrict__ topkw, int* __restrict__ counts, int* __restrict__ lists)
{
    int t = blockIdx.x * 256 + threadIdx.x;
    if (t >= NT) return;

    float scores[NE], sfc[NE], tmp[NE];
    #pragma unroll
    for (int e = 0; e < NE; ++e) {
        float l = logits[(size_t)t * NE + e];
        float s = 1.f / (1.f + __expf(-l));
        scores[e] = s;
        sfc[e] = s + rb[e];
    }
    float gs[NG];
    #pragma unroll
    for (int g = 0; g < NG; ++g) {
        float m1 = -1e30f, m2 = -1e30f;
        #pragma unroll
        for (int j = 0; j < 8; ++j) {
            float v = sfc[g * 8 + j];
            if (v > m1) { m2 = m1; m1 = v; } else if (v > m2) m2 = v;
        }
        gs[g] = m1 + m2;
    }
    int g1 = 0;
    #pragma unroll
    for (int g = 1; g < NG; ++g) if (gs[g] > gs[g1]) g1 = g;
    int g2 = -1;
    #pragma unroll
    for (int g = 0; g < NG; ++g) {
        if (g == g1) continue;
        if (g2 < 0 || gs[g] > gs[g2]) g2 = g;
    }
    #pragma unroll
    for (int e = 0; e < NE; ++e) {
        int g = e >> 3;
        tmp[e] = (g == g1 || g == g2) ? sfc[e] : 0.0f;
    }
    int idx[4]; float wk[4]; float wsum = 0.f;
    #pragma unroll
    for (int k = 0; k < 4; ++k) {
        int best = 0; float bv = -1e30f;
        #pragma unroll
        for (int e = 0; e < NE; ++e) if (tmp[e] > bv) { bv = tmp[e]; best = e; }
        idx[k] = best; tmp[best] = -1e30f;
        wk[k] = scores[best]; wsum += wk[k];
    }
    float inv = SCALE / (wsum + 1e-20f);
    #pragma unroll
    for (int k = 0; k < 4; ++k) {
        int p = t * 4 + k;
        topkw[p] = wk[k] * inv;
        int e = idx[k];
        int pos = atomicAdd(&counts[e], 1);
        lists[e * NT + pos] = p;
    }
}

// ======================================================================================
// NEW PATH: bf16 inputs, global_load_lds staging, linear LDS + XOR-swizzled source/read
// LDS tile layout: [rows][BK] bf16 (64B rows, 4x 16B chunks). Stored chunk c holds global
// chunk c ^ s(row), s(row) = (row>>1)&3; reads XOR the same -> conflict-free & correct.
// ======================================================================================

// fused gate/up + SwiGLU. X bf16 [tokens, HD]; Wg/Wu bf16 [(E,) ND, HD]; Hout bf16 [rows, ND]
template<bool EXPERT, int ND, int BMT>
__global__ void __launch_bounds__(256) gateup2(
    const bf16_t* __restrict__ X, const bf16_t* __restrict__ Wg,
    const bf16_t* __restrict__ Wu, bf16_t* __restrict__ Hout,
    const int* __restrict__ lists, const int* __restrict__ counts)
{
    constexpr int NB = 64;          // n-tile (per B tensor)
    int e = 0, cnt = NT;
    const bf16_t* wg = Wg; const bf16_t* wu = Wu;
    if (EXPERT) {
        e = blockIdx.x; cnt = counts[e];
        wg = Wg + (size_t)e * ND * HD;
        wu = Wu + (size_t)e * ND * HD;
    }
    int mtb = blockIdx.y, ntb = blockIdx.z;
    if (mtb * BMT >= cnt) return;

    constexpr int AU = BMT / 64;    // gld16 per thread for A
    constexpr int MT = BMT / 32;    // m-frags per wave

    __shared__ __align__(16) bf16_t As[2][BMT * BK];
    __shared__ __align__(16) bf16_t Bgs[2][NB * BK];
    __shared__ __align__(16) bf16_t Bus[2][NB * BK];
    __shared__ int rowid[BMT];

    int tid = threadIdx.x;
    if (tid < BMT) {
        int gm = mtb * BMT + tid;
        int mm = gm < cnt ? gm : cnt - 1;
        rowid[tid] = EXPERT ? lists[e * NT + mm] : mm;
    }
    __syncthreads();

    int lane = tid & 63;
    int w = tid >> 6;
    int wm = w & 1, wn = w >> 1;
    int lrow = lane & 15, quad = lane >> 4;
    int chunkL = lane & 3;

    // per-lane staging source pointers (chunk XOR keyed by LDS dest row)
    const bf16_t* asrc[AU];
    #pragma unroll
    for (int i = 0; i < AU; ++i) {
        int row = (w * AU + i) * 16 + (lane >> 2);
        int tok = EXPERT ? (rowid[row] >> 2) : rowid[row];
        int ch = chunkL ^ ((row >> 1) & 3);
        asrc[i] = X + (size_t)tok * HD + ch * 8;
    }
    int nrow = w * 16 + (lane >> 2);
    int nch = chunkL ^ ((nrow >> 1) & 3);
    const bf16_t* bgsrc = wg + (size_t)(ntb * NB + nrow) * HD + nch * 8;
    const bf16_t* busrc = wu + (size_t)(ntb * NB + nrow) * HD + nch * 8;

    // precomputed fragment read offsets (elements), same XOR
    int aoff[MT], goff[2];
    #pragma unroll
    for (int mt = 0; mt < MT; ++mt) {
        int row = wm * (BMT / 2) + mt * 16 + lrow;
        aoff[mt] = row * BK + (quad ^ ((row >> 1) & 3)) * 8;
    }
    #pragma unroll
    for (int nt = 0; nt < 2; ++nt) {
        int row = wn * 32 + nt * 16 + lrow;
        goff[nt] = row * BK + (quad ^ ((row >> 1) & 3)) * 8;
    }

    f32x4 accg[MT][2], accu[MT][2];
    #pragma unroll
    for (int i = 0; i < MT; ++i)
        #pragma unroll
        for (int j = 0; j < 2; ++j) { accg[i][j] = (f32x4){0,0,0,0}; accu[i][j] = (f32x4){0,0,0,0}; }

    auto stage = [&](int buf, int k) {
        #pragma unroll
        for (int i = 0; i < AU; ++i)
            gld16(asrc[i] + k, &As[buf][(w * AU + i) * 512]);
        gld16(bgsrc + k, &Bgs[buf][w * 512]);
        gld16(busrc + k, &Bus[buf][w * 512]);
    };
    auto compute = [&](int buf) {
        bf16x8 af[MT], bg[2], bu[2];
        #pragma unroll
        for (int mt = 0; mt < MT; ++mt) af[mt] = *(const bf16x8*)(&As[buf][aoff[mt]]);
        #pragma unroll
        for (int nt = 0; nt < 2; ++nt) {
            bg[nt] = *(const bf16x8*)(&Bgs[buf][goff[nt]]);
            bu[nt] = *(const bf16x8*)(&Bus[buf][goff[nt]]);
        }
        #pragma unroll
        for (int mt = 0; mt < MT; ++mt)
            #pragma unroll
            for (int nt = 0; nt < 2; ++nt) {
                accg[mt][nt] = __builtin_amdgcn_mfma_f32_16x16x32_bf16(af[mt], bg[nt], accg[mt][nt], 0, 0, 0);
                accu[mt][nt] = __builtin_amdgcn_mfma_f32_16x16x32_bf16(af[mt], bu[nt], accu[mt][nt], 0, 0, 0);
            }
    };

    stage(0, 0);
    __syncthreads();
    int buf = 0;
    for (int k0 = BK; k0 < HD; k0 += BK) {
        stage(buf ^ 1, k0);
        compute(buf);
        __syncthreads();
        buf ^= 1;
    }
    compute(buf);

    // epilogue: h = silu(g)*u, store bf16
    #pragma unroll
    for (int mt = 0; mt < MT; ++mt)
        #pragma unroll
        for (int r = 0; r < 4; ++r) {
            int row_local = wm * (BMT / 2) + mt * 16 + quad * 4 + r;
            int gm = mtb * BMT + row_local;
            if (gm >= cnt) continue;
            int p = rowid[row_local];
            #pragma unroll
            for (int nt = 0; nt < 2; ++nt) {
                int col = ntb * NB + wn * 32 + nt * 16 + lrow;
                float g = accg[mt][nt][r], u = accu[mt][nt][r];
                float h = (g / (1.f + __expf(-g))) * u;
                Hout[(size_t)p * ND + col] = (__bf16)h;
            }
        }
}

// down projection. Hin bf16 [rows, KD]; Wd bf16 [(E,) HD, KD]; out fp32 [NT, HD]
template<bool EXPERT, int KD, int BMT, int NB>
__global__ void __launch_bounds__(256) down2(
    const bf16_t* __restrict__ Hin, const bf16_t* __restrict__ Wd,
    float* __restrict__ out, const int* __restrict__ lists,
    const int* __restrict__ counts, const float* __restrict__ topkw)
{
    int e = 0, cnt = NT;
    const bf16_t* wd = Wd;
    if (EXPERT) {
        e = blockIdx.x; cnt = counts[e];
        wd = Wd + (size_t)e * HD * KD;
    }
    int mtb = blockIdx.y, ntb = blockIdx.z;
    if (mtb * BMT >= cnt) return;

    constexpr int AU = BMT / 64;
    constexpr int BU = NB / 64;
    constexpr int MT = BMT / 32;
    constexpr int NTF = NB / 32;

    __shared__ __align__(16) bf16_t As[2][BMT * BK];
    __shared__ __align__(16) bf16_t Ws[2][NB * BK];
    __shared__ int rowid[BMT];

    int tid = threadIdx.x;
    if (tid < BMT) {
        int gm = mtb * BMT + tid;
        int mm = gm < cnt ? gm : cnt - 1;
        rowid[tid] = EXPERT ? lists[e * NT + mm] : mm;
    }
    __syncthreads();

    int lane = tid & 63;
    int w = tid >> 6;
    int wm = w & 1, wn = w >> 1;
    int lrow = lane & 15, quad = lane >> 4;
    int chunkL = lane & 3;

    const bf16_t* asrc[AU];
    #pragma unroll
    for (int i = 0; i < AU; ++i) {
        int row = (w * AU + i) * 16 + (lane >> 2);
        int ch = chunkL ^ ((row >> 1) & 3);
        asrc[i] = Hin + (size_t)rowid[row] * KD + ch * 8;
    }
    const bf16_t* wsrc[BU];
    #pragma unroll
    for (int i = 0; i < BU; ++i) {
        int row = (w * BU + i) * 16 + (lane >> 2);
        int ch = chunkL ^ ((row >> 1) & 3);
        wsrc[i] = wd + (size_t)(ntb * NB + row) * KD + ch * 8;
    }

    int aoff[MT], woff[NTF];
    #pragma unroll
    for (int mt = 0; mt < MT; ++mt) {
        int row = wm * (BMT / 2) + mt * 16 + lrow;
        aoff[mt] = row * BK + (quad ^ ((row >> 1) & 3)) * 8;
    }
    #pragma unroll
    for (int nt = 0; nt < NTF; ++nt) {
        int row = wn * (NB / 2) + nt * 16 + lrow;
        woff[nt] = row * BK + (quad ^ ((row >> 1) & 3)) * 8;
    }

    f32x4 acc[MT][NTF];
    #pragma unroll
    for (int i = 0; i < MT; ++i)
        #pragma unroll
        for (int j = 0; j < NTF; ++j) acc[i][j] = (f32x4){0,0,0,0};

    auto stage = [&](int buf, int k) {
        #pragma unroll
        for (int i = 0; i < AU; ++i)
            gld16(asrc[i] + k, &As[buf][(w * AU + i) * 512]);
        #pragma unroll
        for (int i = 0; i < BU; ++i)
            gld16(wsrc[i] + k, &Ws[buf][(w * BU + i) * 512]);
    };
    auto compute = [&](int buf) {
        bf16x8 af[MT], br[NTF];
        #pragma unroll
        for (int mt = 0; mt < MT; ++mt) af[mt] = *(const bf16x8*)(&As[buf][aoff[mt]]);
        #pragma unroll
        for (int nt = 0; nt < NTF; ++nt) br[nt] = *(const bf16x8*)(&Ws[buf][woff[nt]]);
        #pragma unroll
        for (int mt = 0; mt < MT; ++mt)
            #pragma unroll
            for (int nt = 0; nt < NTF; ++nt)
                acc[mt][nt] = __builtin_amdgcn_mfma_f32_16x16x32_bf16(af[mt], br[nt], acc[mt][nt], 0, 0, 0);
    };

    stage(0, 0);
    __syncthreads();
    int buf = 0;
    for (int k0 = BK; k0 < KD; k0 += BK) {
        stage(buf ^ 1, k0);
        compute(buf);
        __syncthreads();
        buf ^= 1;
    }
    compute(buf);

    #pragma unroll
    for (int mt = 0; mt < MT; ++mt)
        #pragma unroll
        for (int r = 0; r < 4; ++r) {
            int row_local = wm * (BMT / 2) + mt * 16 + quad * 4 + r;
            int gm = mtb * BMT + row_local;
            if (gm >= cnt) continue;
            int p = rowid[row_local];
            #pragma unroll
            for (int nt = 0; nt < NTF; ++nt) {
                int col = ntb * NB + wn * (NB / 2) + nt * 16 + lrow;
                float val = acc[mt][nt][r];
                if (EXPERT) {
                    float wgt = topkw[p];
                    atomicAdd(&out[(size_t)(p >> 2) * HD + col], wgt * val);
                } else {
                    out[(size_t)p * HD + col] = val;
                }
            }
        }
}

// ======================================================================================
// OLD PATH (fallback when workspace is too small for bf16 mirrors) — known-passing code
// ======================================================================================

__device__ inline bf16x4 cvt4(float4 v) {
    bf16x4 r;
    r[0] = (__bf16)v.x; r[1] = (__bf16)v.y; r[2] = (__bf16)v.z; r[3] = (__bf16)v.w;
    return r;
}

template<bool EXPERT, int ND, int BMT>
__global__ void __launch_bounds__(256) gateup_mfma(
    const float* __restrict__ X, const float* __restrict__ Wg,
    const float* __restrict__ Wu, bf16_t* __restrict__ Hout,
    const int* __restrict__ lists, const int* __restrict__ counts)
{
    int e = 0, cnt = NT;
    const float* wg = Wg; const float* wu = Wu;
    if (EXPERT) {
        e = blockIdx.x; cnt = counts[e];
        wg = Wg + (size_t)e * ND * HD;
        wu = Wu + (size_t)e * ND * HD;
    }
    int mtb = blockIdx.y, ntb = blockIdx.z;
    if (mtb * BMT >= cnt) return;

    __shared__ __align__(16) bf16_t As[BMT * LDA];
    __shared__ __align__(16) bf16_t Bgs[BN * LDA];
    __shared__ __align__(16) bf16_t Bus[BN * LDA];
    __shared__ int rowid[BMT];

    int tid = threadIdx.x;
    if (tid < BMT) {
        int gm = mtb * BMT + tid;
        int mm = gm < cnt ? gm : cnt - 1;
        rowid[tid] = EXPERT ? lists[e * NT + mm] : mm;
    }
    __syncthreads();

    constexpr int AR = (BMT * BK) / (256 * 4);
    constexpr int BR = (BN * BK) / (256 * 4);
    constexpr int MT = BMT / 32;

    int lane = tid & 63;
    int w = tid >> 6;
    int wm = w & 1, wn = w >> 1;
    int lrow = lane & 15, quad = lane >> 4;

    f32x4 accg[MT][2], accu[MT][2];
    #pragma unroll
    for (int i = 0; i < MT; ++i)
        #pragma unroll
        for (int j = 0; j < 2; ++j) { accg[i][j] = (f32x4){0,0,0,0}; accu[i][j] = (f32x4){0,0,0,0}; }

    float4 pa[AR], pbg[BR], pbu[BR];

    #pragma unroll
    for (int r = 0; r < AR; ++r) {
        int idx = r * 256 + tid;
        int row = idx >> 3, kq = idx & 7;
        int tok = EXPERT ? (rowid[row] >> 2) : rowid[row];
        pa[r] = *(const float4*)(X + (size_t)tok * HD + kq * 4);
    }
    #pragma unroll
    for (int r = 0; r < BR; ++r) {
        int idx = r * 256 + tid;
        int n = idx >> 3, kq = idx & 7;
        size_t off = (size_t)(ntb * BN + n) * HD + kq * 4;
        pbg[r] = *(const float4*)(wg + off);
        pbu[r] = *(const float4*)(wu + off);
    }

    for (int k0 = 0; k0 < HD; k0 += BK) {
        #pragma unroll
        for (int r = 0; r < AR; ++r) {
            int idx = r * 256 + tid;
            int row = idx >> 3, kq = idx & 7;
            *(bf16x4*)(As + row * LDA + kq * 4) = cvt4(pa[r]);
        }
        #pragma unroll
        for (int r = 0; r < BR; ++r) {
            int idx = r * 256 + tid;
            int n = idx >> 3, kq = idx & 7;
            *(bf16x4*)(Bgs + n * LDA + kq * 4) = cvt4(pbg[r]);
            *(bf16x4*)(Bus + n * LDA + kq * 4) = cvt4(pbu[r]);
        }
        __syncthreads();

        int k1 = k0 + BK;
        if (k1 < HD) {
            #pragma unroll
            for (int r = 0; r < AR; ++r) {
                int idx = r * 256 + tid;
                int row = idx >> 3, kq = idx & 7;
                int tok = EXPERT ? (rowid[row] >> 2) : rowid[row];
                pa[r] = *(const float4*)(X + (size_t)tok * HD + k1 + kq * 4);
            }
            #pragma unroll
            for (int r = 0; r < BR; ++r) {
                int idx = r * 256 + tid;
                int n = idx >> 3, kq = idx & 7;
                size_t off = (size_t)(ntb * BN + n) * HD + k1 + kq * 4;
                pbg[r] = *(const float4*)(wg + off);
                pbu[r] = *(const float4*)(wu + off);
            }
        }

        bf16x8 af[MT], bg[2], bu[2];
        #pragma unroll
        for (int mt = 0; mt < MT; ++mt)
            af[mt] = *(const bf16x8*)(As + (wm * (BMT / 2) + mt * 16 + lrow) * LDA + quad * 8);
        #pragma unroll
        for (int nt = 0; nt < 2; ++nt) {
            bg[nt] = *(const bf16x8*)(Bgs + (wn * 32 + nt * 16 + lrow) * LDA + quad * 8);
            bu[nt] = *(const bf16x8*)(Bus + (wn * 32 + nt * 16 + lrow) * LDA + quad * 8);
        }
        #pragma unroll
        for (int mt = 0; mt < MT; ++mt)
            #pragma unroll
            for (int nt = 0; nt < 2; ++nt) {
                accg[mt][nt] = __builtin_amdgcn_mfma_f32_16x16x32_bf16(af[mt], bg[nt], accg[mt][nt], 0, 0, 0);
                accu[mt][nt] = __builtin_amdgcn_mfma_f32_16x16x32_bf16(af[mt], bu[nt], accu[mt][nt], 0, 0, 0);
            }
        __syncthreads();
    }

    #pragma unroll
    for (int mt = 0; mt < MT; ++mt)
        #pragma unroll
        for (int r = 0; r < 4; ++r) {
            int row_local = wm * (BMT / 2) + mt * 16 + quad * 4 + r;
            int gm = mtb * BMT + row_local;
            if (gm >= cnt) continue;
            int p = rowid[row_local];
            #pragma unroll
            for (int nt = 0; nt < 2; ++nt) {
                int col = ntb * BN + wn * 32 + nt * 16 + lrow;
                float g = accg[mt][nt][r], u = accu[mt][nt][r];
                float h = (g / (1.f + __expf(-g))) * u;
                Hout[(size_t)p * ND + col] = (__bf16)h;
            }
        }
}

template<bool EXPERT, int KD, int BMT>
__global__ void __launch_bounds__(256) down_mfma(
    const bf16_t* __restrict__ Hin, const float* __restrict__ Wd,
    float* __restrict__ out, const int* __restrict__ lists,
    const int* __restrict__ counts, const float* __restrict__ topkw)
{
    int e = 0, cnt = NT;
    const float* wd = Wd;
    if (EXPERT) {
        e = blockIdx.x; cnt = counts[e];
        wd = Wd + (size_t)e * HD * KD;
    }
    int mtb = blockIdx.y, ntb = blockIdx.z;
    if (mtb * BMT >= cnt) return;

    __shared__ __align__(16) bf16_t As[BMT * LDA];
    __shared__ __align__(16) bf16_t Ws[BN * LDA];
    __shared__ int rowid[BMT];

    int tid = threadIdx.x;
    if (tid < BMT) {
        int gm = mtb * BMT + tid;
        int mm = gm < cnt ? gm : cnt - 1;
        rowid[tid] = EXPERT ? lists[e * NT + mm] : mm;
    }
    __syncthreads();

    constexpr int ARH = (BMT * BK / 8) / 256;
    constexpr int BR = (BN * BK) / (256 * 4);
    constexpr int MT = BMT / 32;

    int lane = tid & 63;
    int w = tid >> 6;
    int wm = w & 1, wn = w >> 1;
    int lrow = lane & 15, quad = lane >> 4;

    f32x4 acc[MT][2];
    #pragma unroll
    for (int i = 0; i < MT; ++i)
        #pragma unroll
        for (int j = 0; j < 2; ++j) acc[i][j] = (f32x4){0,0,0,0};

    bf16x8 pa[ARH];
    float4 pw[BR];

    #pragma unroll
    for (int r = 0; r < ARH; ++r) {
        int idx = r * 256 + tid;
        int row = idx >> 2, c = idx & 3;
        pa[r] = *(const bf16x8*)(Hin + (size_t)rowid[row] * KD + c * 8);
    }
    #pragma unroll
    for (int r = 0; r < BR; ++r) {
        int idx = r * 256 + tid;
        int n = idx >> 3, kq = idx & 7;
        pw[r] = *(const float4*)(wd + (size_t)(ntb * BN + n) * KD + kq * 4);
    }

    for (int k0 = 0; k0 < KD; k0 += BK) {
        #pragma unroll
        for (int r = 0; r < ARH; ++r) {
            int idx = r * 256 + tid;
            int row = idx >> 2, c = idx & 3;
            *(bf16x8*)(As + row * LDA + c * 8) = pa[r];
        }
        #pragma unroll
        for (int r = 0; r < BR; ++r) {
            int idx = r * 256 + tid;
            int n = idx >> 3, kq = idx & 7;
            *(bf16x4*)(Ws + n * LDA + kq * 4) = cvt4(pw[r]);
        }
        __syncthreads();

        int k1 = k0 + BK;
        if (k1 < KD) {
            #pragma unroll
            for (int r = 0; r < ARH; ++r) {
                int idx = r * 256 + tid;
                int row = idx >> 2, c = idx & 3;
                pa[r] = *(const bf16x8*)(Hin + (size_t)rowid[row] * KD + k1 + c * 8);
            }
            #pragma unroll
            for (int r = 0; r < BR; ++r) {
                int idx = r * 256 + tid;
                int n = idx >> 3, kq = idx & 7;
                pw[r] = *(const float4*)(wd + (size_t)(ntb * BN + n) * KD + k1 + kq * 4);
            }
        }

        bf16x8 af[MT], bfr[2];
        #pragma unroll
        for (int mt = 0; mt < MT; ++mt)
            af[mt] = *(const bf16x8*)(As + (wm * (BMT / 2) + mt * 16 + lrow) * LDA + quad * 8);
        #pragma unroll
        for (int nt = 0; nt < 2; ++nt)
            bfr[nt] = *(const bf16x8*)(Ws + (wn * 32 + nt * 16 + lrow) * LDA + quad * 8);
        #pragma unroll
        for (int mt = 0; mt < MT; ++mt)
            #pragma unroll
            for (int nt = 0; nt < 2; ++nt)
                acc[mt][nt] = __builtin_amdgcn_mfma_f32_16x16x32_bf16(af[mt], bfr[nt], acc[mt][nt], 0, 0, 0);
        __syncthreads();
    }

    #pragma unroll
    for (int mt = 0; mt < MT; ++mt)
        #pragma unroll
        for (int r = 0; r < 4; ++r) {
            int row_local = wm * (BMT / 2) + mt * 16 + quad * 4 + r;
            int gm = mtb * BMT + row_local;
            if (gm >= cnt) continue;
            int p = rowid[row_local];
            #pragma unroll
            for (int nt = 0; nt < 2; ++nt) {
                int col = ntb * BN + wn * 32 + nt * 16 + lrow;
                float val = acc[mt][nt][r];
                if (EXPERT) {
                    float wgt = topkw[p];
                    atomicAdd(&out[(size_t)(p >> 2) * HD + col], wgt * val);
                } else {
                    out[(size_t)p * HD + col] = val;
                }
            }
        }
}

extern "C" void kernel_launch(void* const* d_in, const int* in_sizes, int n_in,
                              void* d_out, int out_size, void* d_ws, size_t ws_size,
                              hipStream_t stream) {
    const float* hs  = (const float*)d_in[0];
    const float* rw  = (const float*)d_in[1];
    const float* rb  = (const float*)d_in[2];
    const float* gw  = (const float*)d_in[3];
    const float* uw  = (const float*)d_in[4];
    const float* dw  = (const float*)d_in[5];
    const float* sgw = (const float*)d_in[6];
    const float* suw = (const float*)d_in[7];
    const float* sdw = (const float*)d_in[8];
    float* out = (float*)d_out;
    char* ws = (char*)d_ws;

    constexpr size_t BF16_ELEMS = (size_t)3 * NE * ID * HD   // gate, up, down
                                + (size_t)3 * SHI * HD       // shared gate/up/down
                                + (size_t)NT * HD;           // hs
    constexpr size_t REQ_WS = (size_t)(1 << 20) + BF16_ELEMS * 2 + (size_t)8192 * ID * 2;

    if (ws_size >= REQ_WS) {
        // ---- new path: bf16 mirrors + global_load_lds GEMMs ----
        int*    counts = (int*)ws;                               // 128 B
        float*  topkw  = (float*)(ws + 1024);                    // 32 KB
        int*    lists  = (int*)(ws + 1024 + 32768);              // 256 KB
        float*  logits = (float*)(ws + 1024 + 32768 + 262144);   // 256 KB

        bf16_t* wg_b = (bf16_t*)(ws + (1 << 20));
        bf16_t* wu_b = wg_b + (size_t)NE * ID * HD;
        bf16_t* wd_b = wu_b + (size_t)NE * ID * HD;
        bf16_t* sg_b = wd_b + (size_t)NE * ID * HD;
        bf16_t* su_b = sg_b + (size_t)SHI * HD;
        bf16_t* sd_b = su_b + (size_t)SHI * HD;
        bf16_t* hs_b = sd_b + (size_t)SHI * HD;
        bf16_t* hbuf = hs_b + (size_t)NT * HD;

        convert_all<<<2048, 256, 0, stream>>>(gw, uw, dw, sgw, suw, sdw, hs, wg_b);

        logits_kernel<<<NT / LTOK, 256, 0, stream>>>(hs, rw, logits, counts);
        topk_kernel<<<NT / 256, 256, 0, stream>>>(logits, rb, topkw, counts, lists);

        // shared expert
        gateup2<false, SHI, 64><<<dim3(1, NT / 64, SHI / 64), 256, 0, stream>>>(
            hs_b, sg_b, su_b, hbuf, nullptr, nullptr);
        down2<false, SHI, 64, 64><<<dim3(1, NT / 64, HD / 64), 256, 0, stream>>>(
            hbuf, sd_b, out, nullptr, nullptr, nullptr);

        // routed experts
        gateup2<true, ID, 128><<<dim3(NE, NT / 128, ID / 64), 256, 0, stream>>>(
            hs_b, wg_b, wu_b, hbuf, lists, counts);
        down2<true, ID, 128, 128><<<dim3(NE, NT / 128, HD / 128), 256, 0, stream>>>(
            hbuf, wd_b, out, lists, counts, topkw);
    } else {
        // ---- fallback: previous known-good path (fits in ~9 MB workspace) ----
        int*    counts = (int*)ws;
        float*  topkw  = (float*)(ws + 128);
        int*    lists  = (int*)(ws + 128 + 32768);
        float*  logits = (float*)(ws + 128 + 32768 + 262144);
        bf16_t* hbuf   = (bf16_t*)(ws + 128 + 32768 + 262144 + 262144);

        logits_kernel<<<NT / LTOK, 256, 0, stream>>>(hs, rw, logits, counts);
        topk_kernel<<<NT / 256, 256, 0, stream>>>(logits, rb, topkw, counts, lists);

        gateup_mfma<false, SHI, 64><<<dim3(1, NT / 64, SHI / BN), 256, 0, stream>>>(
            hs, sgw, suw, hbuf, nullptr, nullptr);
        down_mfma<false, SHI, 64><<<dim3(1, NT / 64, HD / BN), 256, 0, stream>>>(
            hbuf, sdw, out, nullptr, nullptr, nullptr);

        gateup_mfma<true, ID, 128><<<dim3(NE, NT / 128, ID / BN), 256, 0, stream>>>(
            hs, gw, uw, hbuf, lists, counts);
        down_mfma<true, ID, 128><<<dim3(NE, NT / 128, HD / BN), 256, 0, stream>>>(
            hbuf, dw, out, lists, counts, topkw);
    }
}

// Round 2
// 395.569 us; speedup vs baseline: 1.0579x; 1.0287x over previous
//
#include <hip/hip_runtime.h>
#include <hip/hip_bf16.h>
#include <math.h>

// Problem constants
#define HD 1024     // hidden H
#define ID 512      // moe intermediate I
#define NE 32       // n experts
#define NT 2048     // tokens T = B*S
#define NG 4        // n_group
#define SHI 1024    // shared intermediate I*N_SHARED
#define SCALE 2.5f

// MFMA GEMM tile params
#define BN 64
#define BK 32
#define LDA 40      // LDS row stride (old fallback path)
#define NCV 4       // extra x-slices in gateup_all doing down-weight conversion

typedef __bf16 bf16_t;
typedef __attribute__((ext_vector_type(8))) __bf16 bf16x8;
typedef __attribute__((ext_vector_type(4))) __bf16 bf16x4;
typedef __attribute__((ext_vector_type(4))) float f32x4;

// async global->LDS, 16B per lane; LDS dest is wave-uniform base (+lane*16 implied)
__device__ __forceinline__ void gld16(const bf16_t* g, bf16_t* l) {
    __builtin_amdgcn_global_load_lds(
        (__attribute__((address_space(1))) void*)g,
        (__attribute__((address_space(3))) void*)l,
        16, 0, 0);
}

// convert 16 fp32 -> 16 bf16 (64B read, 32B write)
__device__ __forceinline__ void cvt16(const float* __restrict__ src, bf16_t* __restrict__ dst) {
    float4 a0 = ((const float4*)src)[0], a1 = ((const float4*)src)[1];
    float4 a2 = ((const float4*)src)[2], a3 = ((const float4*)src)[3];
    bf16x8 o0, o1;
    o0[0]=(__bf16)a0.x; o0[1]=(__bf16)a0.y; o0[2]=(__bf16)a0.z; o0[3]=(__bf16)a0.w;
    o0[4]=(__bf16)a1.x; o0[5]=(__bf16)a1.y; o0[6]=(__bf16)a1.z; o0[7]=(__bf16)a1.w;
    o1[0]=(__bf16)a2.x; o1[1]=(__bf16)a2.y; o1[2]=(__bf16)a2.z; o1[3]=(__bf16)a2.w;
    o1[4]=(__bf16)a3.x; o1[5]=(__bf16)a3.y; o1[6]=(__bf16)a3.z; o1[7]=(__bf16)a3.w;
    ((bf16x8*)dst)[0] = o0;
    ((bf16x8*)dst)[1] = o1;
}

// ---------------- conversion pass A: gate/up/shared-gate/shared-up/hs + zero out ----------------
__global__ void __launch_bounds__(256) convert_A(
    const float* __restrict__ g, const float* __restrict__ u,
    const float* __restrict__ sg, const float* __restrict__ su,
    const float* __restrict__ hs, bf16_t* __restrict__ dst,
    float* __restrict__ outz)
{
    const long long UG = (long long)NE * ID * HD / 16;   // 1048576
    const long long US = (long long)SHI * HD / 16;       // 65536
    const long long UH = (long long)NT * HD / 16;        // 131072
    const long long TOTC = 2 * UG + 2 * US + UH;         // 2359296
    const long long TOT = TOTC + UH;                     // + zero-fill of out
    for (long long c = blockIdx.x * 256LL + threadIdx.x; c < TOT;
         c += (long long)gridDim.x * 256LL) {
        if (c >= TOTC) {
            long long r = c - TOTC;
            float4 z = {0.f, 0.f, 0.f, 0.f};
            float4* p = (float4*)(outz + r * 16);
            p[0] = z; p[1] = z; p[2] = z; p[3] = z;
            continue;
        }
        const float* src;
        long long r = c;
        if (r < UG)                   src = g  + r * 16;
        else if ((r -= UG) < UG)      src = u  + r * 16;
        else if ((r -= UG) < US)      src = sg + r * 16;
        else if ((r -= US) < US)      src = su + r * 16;
        else { r -= US;               src = hs + r * 16; }
        cvt16(src, dst + c * 16);
    }
}

// ---------------- router stage 1: logits GEMM + zero counts ----------------
#define LTOK 8
#define LKC 64
__global__ void __launch_bounds__(256) logits_kernel(
    const float* __restrict__ hs, const float* __restrict__ rw,
    float* __restrict__ logits, int* __restrict__ counts)
{
    if (blockIdx.x == 0 && threadIdx.x < NE) counts[threadIdx.x] = 0;

    __shared__ float Xs[LTOK][68];
    __shared__ float Ws[NE][65];

    int tid = threadIdx.x;
    int t0 = blockIdx.x * LTOK;
    int tslot = tid >> 5, ecol = tid & 31;
    float acc = 0.f;

    for (int k0 = 0; k0 < HD; k0 += LKC) {
        if (tid < 128) {
            int row = tid >> 4, q = tid & 15;
            float4 v = *(const float4*)(hs + (size_t)(t0 + row) * HD + k0 + q * 4);
            *(float4*)(&Xs[row][q * 4]) = v;
        }
        #pragma unroll
        for (int i = 0; i < 8; ++i) {
            int idx = i * 256 + tid;
            int e = idx >> 6, kk = idx & 63;
            Ws[e][kk] = rw[(size_t)e * HD + k0 + kk];
        }
        __syncthreads();
        #pragma unroll 8
        for (int kk = 0; kk < LKC; ++kk)
            acc += Xs[tslot][kk] * Ws[ecol][kk];
        __syncthreads();
    }
    logits[(size_t)(t0 + tslot) * NE + ecol] = acc;
}

// ---------------- router stage 2: per-token top-k ----------------
__global__ void __launch_bounds__(256) topk_kernel(
    const float* __restrict__ logits, const float* __restrict__ rb,
    float* __restrict__ topkw, int* __restrict__ counts, int* __restrict__ lists)
{
    int t = blockIdx.x * 256 + threadIdx.x;
    if (t >= NT) return;

    float scores[NE], sfc[NE], tmp[NE];
    #pragma unroll
    for (int e = 0; e < NE; ++e) {
        float l = logits[(size_t)t * NE + e];
        float s = 1.f / (1.f + __expf(-l));
        scores[e] = s;
        sfc[e] = s + rb[e];
    }
    float gs[NG];
    #pragma unroll
    for (int g = 0; g < NG; ++g) {
        float m1 = -1e30f, m2 = -1e30f;
        #pragma unroll
        for (int j = 0; j < 8; ++j) {
            float v = sfc[g * 8 + j];
            if (v > m1) { m2 = m1; m1 = v; } else if (v > m2) m2 = v;
        }
        gs[g] = m1 + m2;
    }
    int g1 = 0;
    #pragma unroll
    for (int g = 1; g < NG; ++g) if (gs[g] > gs[g1]) g1 = g;
    int g2 = -1;
    #pragma unroll
    for (int g = 0; g < NG; ++g) {
        if (g == g1) continue;
        if (g2 < 0 || gs[g] > gs[g2]) g2 = g;
    }
    #pragma unroll
    for (int e = 0; e < NE; ++e) {
        int g = e >> 3;
        tmp[e] = (g == g1 || g == g2) ? sfc[e] : 0.0f;
    }
    int idx[4]; float wk[4]; float wsum = 0.f;
    #pragma unroll
    for (int k = 0; k < 4; ++k) {
        int best = 0; float bv = -1e30f;
        #pragma unroll
        for (int e = 0; e < NE; ++e) if (tmp[e] > bv) { bv = tmp[e]; best = e; }
        idx[k] = best; tmp[best] = -1e30f;
        wk[k] = scores[best]; wsum += wk[k];
    }
    float inv = SCALE / (wsum + 1e-20f);
    #pragma unroll
    for (int k = 0; k < 4; ++k) {
        int p = t * 4 + k;
        topkw[p] = wk[k] * inv;
        int e = idx[k];
        int pos = atomicAdd(&counts[e], 1);
        lists[e * NT + pos] = p;
    }
}

// ======================================================================================
// FUSED GEMMs: bf16 inputs, global_load_lds staging, linear LDS + XOR-swizzled src/read.
// LDS tile [rows][32] bf16 (64B rows, 4x16B chunks); stored chunk c holds global chunk
// c ^ ((row>>1)&3); reads XOR the same -> conflict-free & correct.
// gateup_all x-layout: [0,32) routed expert | [32,34) shared | [34,38) down-wt convert.
// down_all   x-layout: [0,64) routed (e=x>>1) | [64,66) shared.  All roles atomicAdd out
// (out pre-zeroed in convert_A) since shared/routed blocks run concurrently.
// ======================================================================================

__global__ void __launch_bounds__(256) gateup_all(
    const bf16_t* __restrict__ hs_b,
    const bf16_t* __restrict__ wg_b, const bf16_t* __restrict__ wu_b,
    const bf16_t* __restrict__ sg_b, const bf16_t* __restrict__ su_b,
    bf16_t* __restrict__ hr, bf16_t* __restrict__ hsh,
    const int* __restrict__ lists, const int* __restrict__ counts,
    const float* __restrict__ dwf, const float* __restrict__ sdwf,
    bf16_t* __restrict__ dstB)
{
    int bx = blockIdx.x, mtb = blockIdx.y, zz = blockIdx.z;
    int tid = threadIdx.x;

    if (bx >= 34) {
        // convert-B role: down weights fp32 -> bf16, overlapped with GEMM blocks
        const long long UD = (long long)NE * HD * ID / 16;   // 1048576
        const long long USD = (long long)HD * SHI / 16;      // 65536
        const long long TOT = UD + USD;
        long long c = (((long long)(bx - 34) * 16 + mtb) * 8 + zz) * 256 + tid;
        const long long stride = (long long)NCV * 128 * 256; // 131072
        for (; c < TOT; c += stride) {
            const float* src = (c < UD) ? (dwf + c * 16) : (sdwf + (c - UD) * 16);
            cvt16(src, dstB + c * 16);
        }
        return;
    }

    // ---- GEMM role ----
    constexpr int BMT = 128, NB = 64;
    constexpr int AU = 2, MT = 4;

    int cnt, ntb, ND;
    const bf16_t *wg, *wu;
    bf16_t* hout;
    const int* rlist = nullptr;
    if (bx < 32) {
        int e = bx; cnt = counts[e];
        if (mtb * BMT >= cnt) return;
        ntb = zz;                              // [0, ID/NB=8)
        wg = wg_b + (size_t)e * ID * HD;
        wu = wu_b + (size_t)e * ID * HD;
        hout = hr; ND = ID;
        rlist = lists + e * NT;
    } else {
        cnt = NT;
        ntb = (bx - 32) * 8 + zz;              // [0, SHI/NB=16)
        wg = sg_b; wu = su_b;
        hout = hsh; ND = SHI;
    }

    __shared__ __align__(16) bf16_t As[2][BMT * BK];
    __shared__ __align__(16) bf16_t Bgs[2][NB * BK];
    __shared__ __align__(16) bf16_t Bus[2][NB * BK];
    __shared__ int rowid[BMT];

    if (tid < BMT) {
        int gm = mtb * BMT + tid;
        int mm = gm < cnt ? gm : cnt - 1;
        rowid[tid] = rlist ? rlist[mm] : mm;
    }
    __syncthreads();

    int lane = tid & 63;
    int w = tid >> 6;
    int wm = w & 1, wn = w >> 1;
    int lrow = lane & 15, quad = lane >> 4, chunkL = lane & 3;

    const bf16_t* asrc[AU];
    #pragma unroll
    for (int i = 0; i < AU; ++i) {
        int row = (w * AU + i) * 16 + (lane >> 2);
        int tok = rlist ? (rowid[row] >> 2) : rowid[row];
        int ch = chunkL ^ ((row >> 1) & 3);
        asrc[i] = hs_b + (size_t)tok * HD + ch * 8;
    }
    int nrow = w * 16 + (lane >> 2);
    int nch = chunkL ^ ((nrow >> 1) & 3);
    const bf16_t* bgsrc = wg + (size_t)(ntb * NB + nrow) * HD + nch * 8;
    const bf16_t* busrc = wu + (size_t)(ntb * NB + nrow) * HD + nch * 8;

    int aoff[MT], goff[2];
    #pragma unroll
    for (int mt = 0; mt < MT; ++mt) {
        int row = wm * (BMT / 2) + mt * 16 + lrow;
        aoff[mt] = row * BK + (quad ^ ((row >> 1) & 3)) * 8;
    }
    #pragma unroll
    for (int nt = 0; nt < 2; ++nt) {
        int row = wn * 32 + nt * 16 + lrow;
        goff[nt] = row * BK + (quad ^ ((row >> 1) & 3)) * 8;
    }

    f32x4 accg[MT][2], accu[MT][2];
    #pragma unroll
    for (int i = 0; i < MT; ++i)
        #pragma unroll
        for (int j = 0; j < 2; ++j) { accg[i][j] = (f32x4){0,0,0,0}; accu[i][j] = (f32x4){0,0,0,0}; }

    auto stage = [&](int buf, int k) {
        #pragma unroll
        for (int i = 0; i < AU; ++i)
            gld16(asrc[i] + k, &As[buf][(w * AU + i) * 512]);
        gld16(bgsrc + k, &Bgs[buf][w * 512]);
        gld16(busrc + k, &Bus[buf][w * 512]);
    };
    auto compute = [&](int buf) {
        bf16x8 af[MT], bg[2], bu[2];
        #pragma unroll
        for (int mt = 0; mt < MT; ++mt) af[mt] = *(const bf16x8*)(&As[buf][aoff[mt]]);
        #pragma unroll
        for (int nt = 0; nt < 2; ++nt) {
            bg[nt] = *(const bf16x8*)(&Bgs[buf][goff[nt]]);
            bu[nt] = *(const bf16x8*)(&Bus[buf][goff[nt]]);
        }
        #pragma unroll
        for (int mt = 0; mt < MT; ++mt)
            #pragma unroll
            for (int nt = 0; nt < 2; ++nt) {
                accg[mt][nt] = __builtin_amdgcn_mfma_f32_16x16x32_bf16(af[mt], bg[nt], accg[mt][nt], 0, 0, 0);
                accu[mt][nt] = __builtin_amdgcn_mfma_f32_16x16x32_bf16(af[mt], bu[nt], accu[mt][nt], 0, 0, 0);
            }
    };

    stage(0, 0);
    __syncthreads();
    int buf = 0;
    for (int k0 = BK; k0 < HD; k0 += BK) {
        stage(buf ^ 1, k0);
        compute(buf);
        __syncthreads();
        buf ^= 1;
    }
    compute(buf);

    #pragma unroll
    for (int mt = 0; mt < MT; ++mt)
        #pragma unroll
        for (int r = 0; r < 4; ++r) {
            int row_local = wm * (BMT / 2) + mt * 16 + quad * 4 + r;
            int gm = mtb * BMT + row_local;
            if (gm >= cnt) continue;
            int p = rowid[row_local];
            #pragma unroll
            for (int nt = 0; nt < 2; ++nt) {
                int col = ntb * NB + wn * 32 + nt * 16 + lrow;
                float gv = accg[mt][nt][r], uv = accu[mt][nt][r];
                float h = (gv / (1.f + __expf(-gv))) * uv;
                hout[(size_t)p * ND + col] = (__bf16)h;
            }
        }
}

__global__ void __launch_bounds__(256) down_all(
    const bf16_t* __restrict__ hr, const bf16_t* __restrict__ hsh,
    const bf16_t* __restrict__ wd_b, const bf16_t* __restrict__ sd_b,
    float* __restrict__ out,
    const int* __restrict__ lists, const int* __restrict__ counts,
    const float* __restrict__ topkw)
{
    int bx = blockIdx.x, mtb = blockIdx.y, zz = blockIdx.z;
    int tid = threadIdx.x;

    constexpr int BMT = 128, NB = 64;
    constexpr int AU = 2, MT = 4;

    int cnt, ntb, KD;
    const bf16_t *Hin, *wd;
    const int* rlist = nullptr;
    bool routed;
    if (bx < 64) {
        int e = bx >> 1; cnt = counts[e];
        if (mtb * BMT >= cnt) return;
        ntb = (bx & 1) * 8 + zz;               // [0, HD/NB=16)
        Hin = hr; wd = wd_b + (size_t)e * HD * ID; KD = ID;
        rlist = lists + e * NT;
        routed = true;
    } else {
        cnt = NT;
        ntb = (bx - 64) * 8 + zz;              // [0, HD/NB=16)
        Hin = hsh; wd = sd_b; KD = SHI;
        routed = false;
    }

    __shared__ __align__(16) bf16_t As[2][BMT * BK];
    __shared__ __align__(16) bf16_t Ws[2][NB * BK];
    __shared__ int rowid[BMT];

    if (tid < BMT) {
        int gm = mtb * BMT + tid;
        int mm = gm < cnt ? gm : cnt - 1;
        rowid[tid] = rlist ? rlist[mm] : mm;
    }
    __syncthreads();

    int lane = tid & 63;
    int w = tid >> 6;
    int wm = w & 1, wn = w >> 1;
    int lrow = lane & 15, quad = lane >> 4, chunkL = lane & 3;

    const bf16_t* asrc[AU];
    #pragma unroll
    for (int i = 0; i < AU; ++i) {
        int row = (w * AU + i) * 16 + (lane >> 2);
        int ch = chunkL ^ ((row >> 1) & 3);
        asrc[i] = Hin + (size_t)rowid[row] * KD + ch * 8;
    }
    int nrow = w * 16 + (lane >> 2);
    int nch = chunkL ^ ((nrow >> 1) & 3);
    const bf16_t* wsrc = wd + (size_t)(ntb * NB + nrow) * KD + nch * 8;

    int aoff[MT], woff[2];
    #pragma unroll
    for (int mt = 0; mt < MT; ++mt) {
        int row = wm * (BMT / 2) + mt * 16 + lrow;
        aoff[mt] = row * BK + (quad ^ ((row >> 1) & 3)) * 8;
    }
    #pragma unroll
    for (int nt = 0; nt < 2; ++nt) {
        int row = wn * 32 + nt * 16 + lrow;
        woff[nt] = row * BK + (quad ^ ((row >> 1) & 3)) * 8;
    }

    f32x4 acc[MT][2];
    #pragma unroll
    for (int i = 0; i < MT; ++i)
        #pragma unroll
        for (int j = 0; j < 2; ++j) acc[i][j] = (f32x4){0,0,0,0};

    auto stage = [&](int buf, int k) {
        #pragma unroll
        for (int i = 0; i < AU; ++i)
            gld16(asrc[i] + k, &As[buf][(w * AU + i) * 512]);
        gld16(wsrc + k, &Ws[buf][w * 512]);
    };
    auto compute = [&](int buf) {
        bf16x8 af[MT], br[2];
        #pragma unroll
        for (int mt = 0; mt < MT; ++mt) af[mt] = *(const bf16x8*)(&As[buf][aoff[mt]]);
        #pragma unroll
        for (int nt = 0; nt < 2; ++nt) br[nt] = *(const bf16x8*)(&Ws[buf][woff[nt]]);
        #pragma unroll
        for (int mt = 0; mt < MT; ++mt)
            #pragma unroll
            for (int nt = 0; nt < 2; ++nt)
                acc[mt][nt] = __builtin_amdgcn_mfma_f32_16x16x32_bf16(af[mt], br[nt], acc[mt][nt], 0, 0, 0);
    };

    stage(0, 0);
    __syncthreads();
    int buf = 0;
    for (int k0 = BK; k0 < KD; k0 += BK) {
        stage(buf ^ 1, k0);
        compute(buf);
        __syncthreads();
        buf ^= 1;
    }
    compute(buf);

    #pragma unroll
    for (int mt = 0; mt < MT; ++mt)
        #pragma unroll
        for (int r = 0; r < 4; ++r) {
            int row_local = wm * (BMT / 2) + mt * 16 + quad * 4 + r;
            int gm = mtb * BMT + row_local;
            if (gm >= cnt) continue;
            int p = rowid[row_local];
            #pragma unroll
            for (int nt = 0; nt < 2; ++nt) {
                int col = ntb * NB + wn * 32 + nt * 16 + lrow;
                float val = acc[mt][nt][r];
                if (routed) {
                    float wgt = topkw[p];
                    atomicAdd(&out[(size_t)(p >> 2) * HD + col], wgt * val);
                } else {
                    atomicAdd(&out[(size_t)p * HD + col], val);
                }
            }
        }
}

// ======================================================================================
// OLD PATH (fallback when workspace too small for bf16 mirrors) — known-passing code
// ======================================================================================

__device__ inline bf16x4 cvt4(float4 v) {
    bf16x4 r;
    r[0] = (__bf16)v.x; r[1] = (__bf16)v.y; r[2] = (__bf16)v.z; r[3] = (__bf16)v.w;
    return r;
}

template<bool EXPERT, int ND, int BMT>
__global__ void __launch_bounds__(256) gateup_mfma(
    const float* __restrict__ X, const float* __restrict__ Wg,
    const float* __restrict__ Wu, bf16_t* __restrict__ Hout,
    const int* __restrict__ lists, const int* __restrict__ counts)
{
    int e = 0, cnt = NT;
    const float* wg = Wg; const float* wu = Wu;
    if (EXPERT) {
        e = blockIdx.x; cnt = counts[e];
        wg = Wg + (size_t)e * ND * HD;
        wu = Wu + (size_t)e * ND * HD;
    }
    int mtb = blockIdx.y, ntb = blockIdx.z;
    if (mtb * BMT >= cnt) return;

    __shared__ __align__(16) bf16_t As[BMT * LDA];
    __shared__ __align__(16) bf16_t Bgs[BN * LDA];
    __shared__ __align__(16) bf16_t Bus[BN * LDA];
    __shared__ int rowid[BMT];

    int tid = threadIdx.x;
    if (tid < BMT) {
        int gm = mtb * BMT + tid;
        int mm = gm < cnt ? gm : cnt - 1;
        rowid[tid] = EXPERT ? lists[e * NT + mm] : mm;
    }
    __syncthreads();

    constexpr int AR = (BMT * BK) / (256 * 4);
    constexpr int BR = (BN * BK) / (256 * 4);
    constexpr int MT = BMT / 32;

    int lane = tid & 63;
    int w = tid >> 6;
    int wm = w & 1, wn = w >> 1;
    int lrow = lane & 15, quad = lane >> 4;

    f32x4 accg[MT][2], accu[MT][2];
    #pragma unroll
    for (int i = 0; i < MT; ++i)
        #pragma unroll
        for (int j = 0; j < 2; ++j) { accg[i][j] = (f32x4){0,0,0,0}; accu[i][j] = (f32x4){0,0,0,0}; }

    float4 pa[AR], pbg[BR], pbu[BR];

    #pragma unroll
    for (int r = 0; r < AR; ++r) {
        int idx = r * 256 + tid;
        int row = idx >> 3, kq = idx & 7;
        int tok = EXPERT ? (rowid[row] >> 2) : rowid[row];
        pa[r] = *(const float4*)(X + (size_t)tok * HD + kq * 4);
    }
    #pragma unroll
    for (int r = 0; r < BR; ++r) {
        int idx = r * 256 + tid;
        int n = idx >> 3, kq = idx & 7;
        size_t off = (size_t)(ntb * BN + n) * HD + kq * 4;
        pbg[r] = *(const float4*)(wg + off);
        pbu[r] = *(const float4*)(wu + off);
    }

    for (int k0 = 0; k0 < HD; k0 += BK) {
        #pragma unroll
        for (int r = 0; r < AR; ++r) {
            int idx = r * 256 + tid;
            int row = idx >> 3, kq = idx & 7;
            *(bf16x4*)(As + row * LDA + kq * 4) = cvt4(pa[r]);
        }
        #pragma unroll
        for (int r = 0; r < BR; ++r) {
            int idx = r * 256 + tid;
            int n = idx >> 3, kq = idx & 7;
            *(bf16x4*)(Bgs + n * LDA + kq * 4) = cvt4(pbg[r]);
            *(bf16x4*)(Bus + n * LDA + kq * 4) = cvt4(pbu[r]);
        }
        __syncthreads();

        int k1 = k0 + BK;
        if (k1 < HD) {
            #pragma unroll
            for (int r = 0; r < AR; ++r) {
                int idx = r * 256 + tid;
                int row = idx >> 3, kq = idx & 7;
                int tok = EXPERT ? (rowid[row] >> 2) : rowid[row];
                pa[r] = *(const float4*)(X + (size_t)tok * HD + k1 + kq * 4);
            }
            #pragma unroll
            for (int r = 0; r < BR; ++r) {
                int idx = r * 256 + tid;
                int n = idx >> 3, kq = idx & 7;
                size_t off = (size_t)(ntb * BN + n) * HD + k1 + kq * 4;
                pbg[r] = *(const float4*)(wg + off);
                pbu[r] = *(const float4*)(wu + off);
            }
        }

        bf16x8 af[MT], bg[2], bu[2];
        #pragma unroll
        for (int mt = 0; mt < MT; ++mt)
            af[mt] = *(const bf16x8*)(As + (wm * (BMT / 2) + mt * 16 + lrow) * LDA + quad * 8);
        #pragma unroll
        for (int nt = 0; nt < 2; ++nt) {
            bg[nt] = *(const bf16x8*)(Bgs + (wn * 32 + nt * 16 + lrow) * LDA + quad * 8);
            bu[nt] = *(const bf16x8*)(Bus + (wn * 32 + nt * 16 + lrow) * LDA + quad * 8);
        }
        #pragma unroll
        for (int mt = 0; mt < MT; ++mt)
            #pragma unroll
            for (int nt = 0; nt < 2; ++nt) {
                accg[mt][nt] = __builtin_amdgcn_mfma_f32_16x16x32_bf16(af[mt], bg[nt], accg[mt][nt], 0, 0, 0);
                accu[mt][nt] = __builtin_amdgcn_mfma_f32_16x16x32_bf16(af[mt], bu[nt], accu[mt][nt], 0, 0, 0);
            }
        __syncthreads();
    }

    #pragma unroll
    for (int mt = 0; mt < MT; ++mt)
        #pragma unroll
        for (int r = 0; r < 4; ++r) {
            int row_local = wm * (BMT / 2) + mt * 16 + quad * 4 + r;
            int gm = mtb * BMT + row_local;
            if (gm >= cnt) continue;
            int p = rowid[row_local];
            #pragma unroll
            for (int nt = 0; nt < 2; ++nt) {
                int col = ntb * BN + wn * 32 + nt * 16 + lrow;
                float g = accg[mt][nt][r], u = accu[mt][nt][r];
                float h = (g / (1.f + __expf(-g))) * u;
                Hout[(size_t)p * ND + col] = (__bf16)h;
            }
        }
}

template<bool EXPERT, int KD, int BMT>
__global__ void __launch_bounds__(256) down_mfma(
    const bf16_t* __restrict__ Hin, const float* __restrict__ Wd,
    float* __restrict__ out, const int* __restrict__ lists,
    const int* __restrict__ counts, const float* __restrict__ topkw)
{
    int e = 0, cnt = NT;
    const float* wd = Wd;
    if (EXPERT) {
        e = blockIdx.x; cnt = counts[e];
        wd = Wd + (size_t)e * HD * KD;
    }
    int mtb = blockIdx.y, ntb = blockIdx.z;
    if (mtb * BMT >= cnt) return;

    __shared__ __align__(16) bf16_t As[BMT * LDA];
    __shared__ __align__(16) bf16_t Ws[BN * LDA];
    __shared__ int rowid[BMT];

    int tid = threadIdx.x;
    if (tid < BMT) {
        int gm = mtb * BMT + tid;
        int mm = gm < cnt ? gm : cnt - 1;
        rowid[tid] = EXPERT ? lists[e * NT + mm] : mm;
    }
    __syncthreads();

    constexpr int ARH = (BMT * BK / 8) / 256;
    constexpr int BR = (BN * BK) / (256 * 4);
    constexpr int MT = BMT / 32;

    int lane = tid & 63;
    int w = tid >> 6;
    int wm = w & 1, wn = w >> 1;
    int lrow = lane & 15, quad = lane >> 4;

    f32x4 acc[MT][2];
    #pragma unroll
    for (int i = 0; i < MT; ++i)
        #pragma unroll
        for (int j = 0; j < 2; ++j) acc[i][j] = (f32x4){0,0,0,0};

    bf16x8 pa[ARH];
    float4 pw[BR];

    #pragma unroll
    for (int r = 0; r < ARH; ++r) {
        int idx = r * 256 + tid;
        int row = idx >> 2, c = idx & 3;
        pa[r] = *(const bf16x8*)(Hin + (size_t)rowid[row] * KD + c * 8);
    }
    #pragma unroll
    for (int r = 0; r < BR; ++r) {
        int idx = r * 256 + tid;
        int n = idx >> 3, kq = idx & 7;
        pw[r] = *(const float4*)(wd + (size_t)(ntb * BN + n) * KD + kq * 4);
    }

    for (int k0 = 0; k0 < KD; k0 += BK) {
        #pragma unroll
        for (int r = 0; r < ARH; ++r) {
            int idx = r * 256 + tid;
            int row = idx >> 2, c = idx & 3;
            *(bf16x8*)(As + row * LDA + c * 8) = pa[r];
        }
        #pragma unroll
        for (int r = 0; r < BR; ++r) {
            int idx = r * 256 + tid;
            int n = idx >> 3, kq = idx & 7;
            *(bf16x4*)(Ws + n * LDA + kq * 4) = cvt4(pw[r]);
        }
        __syncthreads();

        int k1 = k0 + BK;
        if (k1 < KD) {
            #pragma unroll
            for (int r = 0; r < ARH; ++r) {
                int idx = r * 256 + tid;
                int row = idx >> 2, c = idx & 3;
                pa[r] = *(const bf16x8*)(Hin + (size_t)rowid[row] * KD + k1 + c * 8);
            }
            #pragma unroll
            for (int r = 0; r < BR; ++r) {
                int idx = r * 256 + tid;
                int n = idx >> 3, kq = idx & 7;
                pw[r] = *(const float4*)(wd + (size_t)(ntb * BN + n) * KD + k1 + kq * 4);
            }
        }

        bf16x8 af[MT], bfr[2];
        #pragma unroll
        for (int mt = 0; mt < MT; ++mt)
            af[mt] = *(const bf16x8*)(As + (wm * (BMT / 2) + mt * 16 + lrow) * LDA + quad * 8);
        #pragma unroll
        for (int nt = 0; nt < 2; ++nt)
            bfr[nt] = *(const bf16x8*)(Ws + (wn * 32 + nt * 16 + lrow) * LDA + quad * 8);
        #pragma unroll
        for (int mt = 0; mt < MT; ++mt)
            #pragma unroll
            for (int nt = 0; nt < 2; ++nt)
                acc[mt][nt] = __builtin_amdgcn_mfma_f32_16x16x32_bf16(af[mt], bfr[nt], acc[mt][nt], 0, 0, 0);
        __syncthreads();
    }

    #pragma unroll
    for (int mt = 0; mt < MT; ++mt)
        #pragma unroll
        for (int r = 0; r < 4; ++r) {
            int row_local = wm * (BMT / 2) + mt * 16 + quad * 4 + r;
            int gm = mtb * BMT + row_local;
            if (gm >= cnt) continue;
            int p = rowid[row_local];
            #pragma unroll
            for (int nt = 0; nt < 2; ++nt) {
                int col = ntb * BN + wn * 32 + nt * 16 + lrow;
                float val = acc[mt][nt][r];
                if (EXPERT) {
                    float wgt = topkw[p];
                    atomicAdd(&out[(size_t)(p >> 2) * HD + col], wgt * val);
                } else {
                    out[(size_t)p * HD + col] = val;
                }
            }
        }
}

extern "C" void kernel_launch(void* const* d_in, const int* in_sizes, int n_in,
                              void* d_out, int out_size, void* d_ws, size_t ws_size,
                              hipStream_t stream) {
    const float* hs  = (const float*)d_in[0];
    const float* rw  = (const float*)d_in[1];
    const float* rb  = (const float*)d_in[2];
    const float* gw  = (const float*)d_in[3];
    const float* uw  = (const float*)d_in[4];
    const float* dw  = (const float*)d_in[5];
    const float* sgw = (const float*)d_in[6];
    const float* suw = (const float*)d_in[7];
    const float* sdw = (const float*)d_in[8];
    float* out = (float*)d_out;
    char* ws = (char*)d_ws;

    constexpr size_t MIR_A = 2 * (size_t)NE * ID * HD + 2 * (size_t)SHI * HD + (size_t)NT * HD;
    constexpr size_t MIR_B = (size_t)NE * ID * HD + (size_t)SHI * HD;
    constexpr size_t HR_E  = (size_t)NT * 4 * ID;
    constexpr size_t HSH_E = (size_t)NT * SHI;
    constexpr size_t REQ_WS = (size_t)(1 << 20) + (MIR_A + MIR_B + HR_E + HSH_E) * 2;

    if (ws_size >= REQ_WS) {
        // ---- fused path ----
        int*    counts = (int*)ws;                               // 128 B
        float*  topkw  = (float*)(ws + 1024);                    // 32 KB
        int*    lists  = (int*)(ws + 1024 + 32768);              // 256 KB
        float*  logits = (float*)(ws + 1024 + 32768 + 262144);   // 256 KB

        bf16_t* mir  = (bf16_t*)(ws + (1 << 20));
        bf16_t* wg_b = mir;
        bf16_t* wu_b = wg_b + (size_t)NE * ID * HD;
        bf16_t* sg_b = wu_b + (size_t)NE * ID * HD;
        bf16_t* su_b = sg_b + (size_t)SHI * HD;
        bf16_t* hs_b = su_b + (size_t)SHI * HD;
        bf16_t* wd_b = hs_b + (size_t)NT * HD;      // convert-B dst
        bf16_t* sd_b = wd_b + (size_t)NE * ID * HD;
        bf16_t* hr   = sd_b + (size_t)SHI * HD;
        bf16_t* hsh  = hr + HR_E;

        logits_kernel<<<NT / LTOK, 256, 0, stream>>>(hs, rw, logits, counts);
        topk_kernel<<<NT / 256, 256, 0, stream>>>(logits, rb, topkw, counts, lists);
        convert_A<<<2048, 256, 0, stream>>>(gw, uw, sgw, suw, hs, mir, out);
        gateup_all<<<dim3(34 + NCV, 16, 8), 256, 0, stream>>>(
            hs_b, wg_b, wu_b, sg_b, su_b, hr, hsh, lists, counts, dw, sdw, wd_b);
        down_all<<<dim3(66, 16, 8), 256, 0, stream>>>(
            hr, hsh, wd_b, sd_b, out, lists, counts, topkw);
    } else {
        // ---- fallback: original known-good path (fits in ~9 MB workspace) ----
        int*    counts = (int*)ws;
        float*  topkw  = (float*)(ws + 128);
        int*    lists  = (int*)(ws + 128 + 32768);
        float*  logits = (float*)(ws + 128 + 32768 + 262144);
        bf16_t* hbuf   = (bf16_t*)(ws + 128 + 32768 + 262144 + 262144);

        logits_kernel<<<NT / LTOK, 256, 0, stream>>>(hs, rw, logits, counts);
        topk_kernel<<<NT / 256, 256, 0, stream>>>(logits, rb, topkw, counts, lists);

        gateup_mfma<false, SHI, 64><<<dim3(1, NT / 64, SHI / BN), 256, 0, stream>>>(
            hs, sgw, suw, hbuf, nullptr, nullptr);
        down_mfma<false, SHI, 64><<<dim3(1, NT / 64, HD / BN), 256, 0, stream>>>(
            hbuf, sdw, out, nullptr, nullptr, nullptr);

        gateup_mfma<true, ID, 128><<<dim3(NE, NT / 128, ID / BN), 256, 0, stream>>>(
            hs, gw, uw, hbuf, lists, counts);
        down_mfma<true, ID, 128><<<dim3(NE, NT / 128, HD / BN), 256, 0, stream>>>(
            hbuf, dw, out, lists, counts, topkw);
    }
}